// Round 3
// baseline (132.286 us; speedup 1.0000x reference)
//
#include <hip/hip_runtime.h>

// MaskToken: B=4, L=4096, D=1024, NUM_KEEP=1024 (sorted idx_keep), NUM_DROP=3072.
// Outputs (concat, float32 view):
//   out0 = outputs_dropped  [B, NUM_KEEP, D]   = gather of kept rows
//   out1 = outputs_masked   [B, L, D]          = kept rows passthrough, dropped rows = mask_embedding
//   out2 = mask_drop        [L]                = 1.0 where dropped else 0.0
//   out3 = idx_keep         [NUM_KEEP]         = written as float values
//
// One block per l (4096 blocks): amortizes the rank binary-search across all 4
// batches, 4 independent load/store chains per thread. Nontemporal loads/stores
// (native ext_vector float4 — HIP_vector_type is rejected by the builtin) for
// the streaming ~100 MB of traffic.

#define B_ 4
#define L_ 4096
#define D_ 1024
#define NKEEP_ 1024
#define D4_ (D_ / 4)

typedef float v4f __attribute__((ext_vector_type(4)));

__global__ __launch_bounds__(256) void masktoken_kernel(
    const v4f* __restrict__ in,           // [B*L*D/4]
    const v4f* __restrict__ me,           // [D/4] mask embedding
    const int* __restrict__ idx_keep,     // [NKEEP_] sorted ascending
    v4f*   __restrict__ out0,             // [B*NKEEP_*D/4]
    v4f*   __restrict__ out1,             // [B*L*D/4]
    float* __restrict__ out2,             // [L]
    float* __restrict__ out3)             // [NKEEP_]
{
    const int l = blockIdx.x;             // 0 .. L-1
    const int t = threadIdx.x;            // 0..255 -> float4 slot within a row

    // lower_bound(idx_keep, l) — workgroup-uniform (idx_keep is 4KB, cache-hot)
    int lo = 0, hi = NKEEP_;
    #pragma unroll
    for (int i = 0; i < 10; ++i) {        // 2^10 == NKEEP_
        int mid = (lo + hi) >> 1;
        if (idx_keep[mid] < l) lo = mid + 1; else hi = mid;
    }
    const int r = (lo < NKEEP_ && idx_keep[lo] == l) ? lo : -1;

    if (t == 0) {
        out2[l] = (r < 0) ? 1.0f : 0.0f;
        if (r >= 0) out3[r] = (float)l;   // idx_keep[r] == l by construction
    }

    if (r >= 0) {
        // kept row: 4 independent copy chains (one per batch)
        #pragma unroll
        for (int b = 0; b < B_; ++b) {
            const size_t src = ((size_t)b * L_ + (size_t)l) * D4_ + t;
            v4f v = __builtin_nontemporal_load(&in[src]);
            __builtin_nontemporal_store(v, &out1[src]);
            __builtin_nontemporal_store(v, &out0[((size_t)b * NKEEP_ + (size_t)r) * D4_ + t]);
        }
    } else {
        // dropped row: broadcast mask embedding (me stays L1-cached — normal load)
        const v4f m = me[t];
        #pragma unroll
        for (int b = 0; b < B_; ++b) {
            __builtin_nontemporal_store(m, &out1[((size_t)b * L_ + (size_t)l) * D4_ + t]);
        }
    }
}

extern "C" void kernel_launch(void* const* d_in, const int* in_sizes, int n_in,
                              void* d_out, int out_size, void* d_ws, size_t ws_size,
                              hipStream_t stream) {
    const v4f* in  = (const v4f*)d_in[0];             // inputs [B,L,D]
    const v4f* me  = (const v4f*)d_in[1];             // mask_embedding [D]
    const int* idx = (const int*)d_in[2];             // idx_keep [NKEEP_]

    float* out = (float*)d_out;
    v4f*   out0 = (v4f*)out;                                      // B*NKEEP_*D
    v4f*   out1 = (v4f*)(out + (size_t)B_ * NKEEP_ * D_);         // B*L*D
    float* out2 = out + (size_t)B_ * NKEEP_ * D_ + (size_t)B_ * L_ * D_;  // L
    float* out3 = out2 + L_;                                      // NKEEP_

    dim3 grid(L_);
    dim3 block(256);
    masktoken_kernel<<<grid, block, 0, stream>>>(in, me, idx, out0, out1, out2, out3);
}